// Round 9
// baseline (459.337 us; speedup 1.0000x reference)
//
#include <hip/hip_runtime.h>

#define EPS 1e-5f

typedef short sh8 __attribute__((ext_vector_type(8)));    // 8 x bf16 (4 VGPR)
typedef float f32x4 __attribute__((ext_vector_type(4)));  // MFMA acc frag

__device__ __forceinline__ ushort f2b(float f) {
    unsigned u = __float_as_uint(f);
    u += 0x7fffu + ((u >> 16) & 1u);          // RNE
    return (ushort)(u >> 16);
}

// ====== InstanceNorm stats: DETERMINISTIC + STABLE (two-phase, 1 blk/chan) =====
// phase 1: mean; phase 2: sum((v-m)^2)  -> st[2ch]=mean, st[2ch+1]=var
// (E[x^2]-m^2 catastrophically cancels on near-constant channels; the reference
//  uses the stable form, so we must too.)
__global__ __launch_bounds__(256) void istat2_k(const float* __restrict__ in,
                                                float* st, int HW)
{
    __shared__ float sh[256];
    int ch = blockIdx.x;
    const float* p = in + (size_t)ch * HW;
    float s = 0.f;
    for (int i = threadIdx.x * 4; i < HW; i += 1024) {
        float4 v = *(const float4*)(p + i);
        s += v.x + v.y + v.z + v.w;
    }
    sh[threadIdx.x] = s;
    __syncthreads();
    for (int o = 128; o > 0; o >>= 1) {
        if ((int)threadIdx.x < o) sh[threadIdx.x] += sh[threadIdx.x + o];
        __syncthreads();
    }
    float m = sh[0] / (float)HW;
    __syncthreads();
    float s2 = 0.f;
    for (int i = threadIdx.x * 4; i < HW; i += 1024) {
        float4 v = *(const float4*)(p + i);
        float d0 = v.x - m, d1 = v.y - m, d2 = v.z - m, d3 = v.w - m;
        s2 += d0 * d0 + d1 * d1 + d2 * d2 + d3 * d3;
    }
    sh[threadIdx.x] = s2;
    __syncthreads();
    for (int o = 128; o > 0; o >>= 1) {
        if ((int)threadIdx.x < o) sh[threadIdx.x] += sh[threadIdx.x + o];
        __syncthreads();
    }
    if (threadIdx.x == 0) {
        st[2 * ch]     = m;
        st[2 * ch + 1] = sh[0] / (float)HW;
    }
}

// apply (mode 0: r, mode 2: v+2r); st holds (mean, var)
__global__ __launch_bounds__(256) void iapply_k(const float* in, const float* st,
                                                float* out, int HW, int mode)
{
    int i4 = (blockIdx.x * 256 + threadIdx.x) * 4;
    int ch = i4 / HW;
    float m = st[2 * ch];
    float inv = rsqrtf(st[2 * ch + 1] + EPS);
    float4 v = *(const float4*)(in + i4);
    float4 r;
    r.x = (v.x - m) * inv; r.y = (v.y - m) * inv;
    r.z = (v.z - m) * inv; r.w = (v.w - m) * inv;
    if (mode == 2) {
        r.x = v.x + 2.f * r.x; r.y = v.y + 2.f * r.y;
        r.z = v.z + 2.f * r.z; r.w = v.w + 2.f * r.w;
    }
    *(float4*)(out + i4) = r;
}

// ================= stage: NCHW f32 -> (padded) NHWC bf16 =======================
__global__ __launch_bounds__(256) void pad_k(const float* __restrict__ in,
    ushort* __restrict__ ob, int C, int H, int W, int pad, int n4)
{
    int idx = blockIdx.x * 256 + threadIdx.x;
    if (idx >= n4) return;
    int b = blockIdx.y;
    int cpp = C >> 2;
    int pp = idx / cpp, c0 = (idx - pp * cpp) * 4;
    int Wp = W + 2 * pad, Hp = H + 2 * pad;
    int yp = pp / Wp, xp = pp - yp * Wp;
    int y = yp - pad, x = xp - pad;
    ushort4 o;
    if (y >= 0 && y < H && x >= 0 && x < W) {
        const float* ib = in + ((size_t)b * C) * H * W + (size_t)y * W + x;
        size_t HW = (size_t)H * W;
        o.x = f2b(ib[(size_t)(c0    ) * HW]);
        o.y = f2b(ib[(size_t)(c0 + 1) * HW]);
        o.z = f2b(ib[(size_t)(c0 + 2) * HW]);
        o.w = f2b(ib[(size_t)(c0 + 3) * HW]);
    } else { o.x = o.y = o.z = o.w = 0; }
    *(ushort4*)(ob + ((size_t)b * Hp * Wp + pp) * C + c0) = o;
}

// ================= weight transforms to bf16 ===================================
__global__ __launch_bounds__(256) void wtb_k(const float* __restrict__ w,
    ushort* __restrict__ wb, int Ci, int n)
{
    int idx = blockIdx.x * 256 + threadIdx.x;
    if (idx >= n) return;
    int co = idx / (9 * Ci);
    int r = idx - co * 9 * Ci;
    int t = r / Ci, ci = r - t * Ci;
    wb[idx] = f2b(w[((size_t)co * Ci + ci) * 9 + t]);
}
__global__ __launch_bounds__(256) void wtb2_k(const float* __restrict__ w,
    ushort* __restrict__ wb, int Ci, int Cout, int n)
{
    int idx = blockIdx.x * 256 + threadIdx.x;
    if (idx >= n) return;
    int to = idx / Ci, ci = idx - to * Ci;
    int t = to / Cout, o = to - t * Cout;
    wb[idx] = f2b(w[((size_t)ci * Cout + o) * 9 + t]);
}

// ================= MFMA GEMM v2: reg-tiled 2x2, software-pipelined =============
// wave: 32 px x 32 n; NWX=2: block 64px x 64n (2x2 waves); NWX=1: 128px x 32n
template<int CI, int TAPS, int NWX>
__global__ __launch_bounds__(256) void mg2_k(
    const ushort* __restrict__ inb, const ushort* __restrict__ wb,
    const float* __restrict__ bias, float* __restrict__ outp,
    int wshift, int Wp, int NS, int CSL, int nchs, size_t SS,
    size_t in_bstride, size_t out_bstride, int HW)
{
    int z = blockIdx.z;
    int b = z / NS, sl = z - b * NS;
    int cilo = sl * CSL;
    int tid = threadIdx.x;
    int wv = tid >> 6, l = tid & 63;
    int lane16 = l & 15, quad = l >> 4;
    int klane = quad * 8;
    int wy, wx;
    if (NWX == 2) { wy = wv & 1; wx = wv >> 1; }
    else          { wy = wv;     wx = 0; }
    const int PXB = (NWX == 2) ? 64 : 128;
    int pb = blockIdx.x * PXB + wy * 32;
    int nb = blockIdx.y * (NWX * 32) + wx * 32;

    int base[2];
    #pragma unroll
    for (int i = 0; i < 2; i++) {
        int pm = pb + i * 16 + lane16;
        if (TAPS == 9) {
            int W = 1 << wshift;
            int y = pm >> wshift, xx = pm & (W - 1);
            base[i] = (y + 1) * Wp + (xx + 1);
        } else base[i] = pm;
    }
    int nn[2];
    nn[0] = nb + lane16; nn[1] = nb + 16 + lane16;

    const ushort* inbb = inb + (size_t)b * in_bstride + cilo + klane;
    const ushort* wbb  = wb + cilo + klane;

    f32x4 vz = {0.f, 0.f, 0.f, 0.f};
    f32x4 acc[2][2] = {{vz, vz}, {vz, vz}};
    sh8 a[2], bf[2], an[2], bn[2];
    int totk = TAPS << nchs;

    #define LDK(kk, av, bv) { \
        int t_ = (kk) >> nchs, c_ = (kk) - (t_ << nchs); \
        int dof_ = 0; \
        if (TAPS == 9) { \
            int dy_ = (t_ * 43) >> 7; \
            int dx_ = t_ - dy_ * 3; \
            dof_ = (dy_ - 1) * Wp + (dx_ - 1); \
        } \
        int coff_ = c_ << 5; \
        av[0] = *(const sh8*)(inbb + (size_t)(base[0] + dof_) * CI + coff_); \
        av[1] = *(const sh8*)(inbb + (size_t)(base[1] + dof_) * CI + coff_); \
        bv[0] = *(const sh8*)(wbb + ((size_t)nn[0] * TAPS + t_) * CI + coff_); \
        bv[1] = *(const sh8*)(wbb + ((size_t)nn[1] * TAPS + t_) * CI + coff_); \
    }

    LDK(0, a, bf)
    for (int kk = 0; kk < totk; kk++) {
        if (kk + 1 < totk) LDK(kk + 1, an, bn)
        acc[0][0] = __builtin_amdgcn_mfma_f32_16x16x32_bf16(a[0], bf[0], acc[0][0], 0, 0, 0);
        acc[0][1] = __builtin_amdgcn_mfma_f32_16x16x32_bf16(a[0], bf[1], acc[0][1], 0, 0, 0);
        acc[1][0] = __builtin_amdgcn_mfma_f32_16x16x32_bf16(a[1], bf[0], acc[1][0], 0, 0, 0);
        acc[1][1] = __builtin_amdgcn_mfma_f32_16x16x32_bf16(a[1], bf[1], acc[1][1], 0, 0, 0);
        a[0] = an[0]; a[1] = an[1]; bf[0] = bn[0]; bf[1] = bn[1];
    }
    #undef LDK

    float* ob = outp + (size_t)sl * SS + (size_t)b * out_bstride;
    #pragma unroll
    for (int j = 0; j < 2; j++) {
        float bb = bias ? bias[nn[j]] : 0.f;
        #pragma unroll
        for (int i = 0; i < 2; i++) {
            int p0 = pb + i * 16 + quad * 4;
            *(float4*)(ob + (size_t)nn[j] * HW + p0) =
                make_float4(acc[i][j][0] + bb, acc[i][j][1] + bb,
                            acc[i][j][2] + bb, acc[i][j][3] + bb);
        }
    }
}

// ================= Direct 3x3 conv fp32 (final 32->3) ==========================
template<int NCO>
__global__ __launch_bounds__(256) void conv3x3_d(const float* __restrict__ in,
    const float* __restrict__ w, const float* __restrict__ bias,
    float* __restrict__ outp, int Ci, int CS, int H, int W, int Co, int NS,
    size_t SS)
{
    int z = blockIdx.z;
    int b = z / NS, sl = z - b * NS;
    int WC = W >> 2;
    int idx = blockIdx.x * 256 + threadIdx.x;
    int xc = idx % WC, y = idx / WC;
    int x0 = xc << 2;
    bool lz = (x0 == 0), rz = (x0 + 4 == W);
    int co0 = blockIdx.y * NCO;
    float acc[NCO][4];
    #pragma unroll
    for (int j = 0; j < NCO; j++)
        #pragma unroll
        for (int p = 0; p < 4; p++) acc[j][p] = 0.f;

    const float* ib = in + ((size_t)b * Ci + sl * CS) * H * W;
    for (int ci = 0; ci < CS; ci++) {
        const float* ic = ib + (size_t)ci * H * W;
        float e[3][6];
        #pragma unroll
        for (int r = 0; r < 3; r++) {
            int yy = y + r - 1;
            float4 v = make_float4(0.f, 0.f, 0.f, 0.f);
            if (yy >= 0 && yy < H)
                v = *(const float4*)(ic + (size_t)yy * W + x0);
            float lf = __shfl_up(v.w, 1);
            float rt = __shfl_down(v.x, 1);
            e[r][0] = lz ? 0.f : lf;
            e[r][1] = v.x; e[r][2] = v.y; e[r][3] = v.z; e[r][4] = v.w;
            e[r][5] = rz ? 0.f : rt;
        }
        int cig = sl * CS + ci;
        #pragma unroll
        for (int j = 0; j < NCO; j++) {
            const float* wj = w + ((size_t)(co0 + j) * Ci + cig) * 9;
            #pragma unroll
            for (int r = 0; r < 3; r++) {
                float w0 = wj[3 * r], w1 = wj[3 * r + 1], w2 = wj[3 * r + 2];
                #pragma unroll
                for (int p = 0; p < 4; p++)
                    acc[j][p] = fmaf(e[r][p], w0,
                                fmaf(e[r][p + 1], w1,
                                fmaf(e[r][p + 2], w2, acc[j][p])));
            }
        }
    }
    size_t HW = (size_t)H * W;
    #pragma unroll
    for (int j = 0; j < NCO; j++) {
        float bb = bias ? bias[co0 + j] : 0.f;
        float4 o = make_float4(acc[j][0] + bb, acc[j][1] + bb,
                               acc[j][2] + bb, acc[j][3] + bb);
        float* op = outp + (size_t)sl * SS
                  + ((size_t)b * Co + co0 + j) * HW + (size_t)y * W + x0;
        *(float4*)op = o;
    }
}

// ================= Direct 1x1 conv fp32 ========================================
template<int NCO>
__global__ __launch_bounds__(256) void conv1x1_d(const float* __restrict__ in,
    const float* __restrict__ w, float* __restrict__ outp,
    int C, int CS, int HW, int NS, size_t SS)
{
    int z = blockIdx.z;
    int b = z / NS, sl = z - b * NS;
    int x0 = (blockIdx.x * 256 + threadIdx.x) * 4;
    int co0 = blockIdx.y * NCO;
    float acc[NCO][4];
    #pragma unroll
    for (int j = 0; j < NCO; j++)
        #pragma unroll
        for (int p = 0; p < 4; p++) acc[j][p] = 0.f;
    const float* ib = in + ((size_t)b * C + sl * CS) * HW;
    for (int ci = 0; ci < CS; ci++) {
        float4 v = *(const float4*)(ib + (size_t)ci * HW + x0);
        int cig = sl * CS + ci;
        #pragma unroll
        for (int j = 0; j < NCO; j++) {
            float wv = w[(size_t)(co0 + j) * C + cig];
            acc[j][0] = fmaf(v.x, wv, acc[j][0]);
            acc[j][1] = fmaf(v.y, wv, acc[j][1]);
            acc[j][2] = fmaf(v.z, wv, acc[j][2]);
            acc[j][3] = fmaf(v.w, wv, acc[j][3]);
        }
    }
    #pragma unroll
    for (int j = 0; j < NCO; j++) {
        float* op = outp + (size_t)sl * SS + ((size_t)b * C + co0 + j) * HW + x0;
        *(float4*)op = make_float4(acc[j][0], acc[j][1], acc[j][2], acc[j][3]);
    }
}

// ================= reduce partials =============================================
__global__ __launch_bounds__(256) void reduce_k(const float* __restrict__ part,
    const float* __restrict__ bias, const float* res, float* out,
    int HW, int Co, int NS, size_t SS)
{
    int i4 = (blockIdx.x * 256 + threadIdx.x) * 4;
    float4 a = make_float4(0.f, 0.f, 0.f, 0.f);
    for (int s = 0; s < NS; s++) {
        float4 p = *(const float4*)(part + (size_t)s * SS + i4);
        a.x += p.x; a.y += p.y; a.z += p.z; a.w += p.w;
    }
    int c = (i4 / HW) % Co;
    float bb = bias[c];
    if (res) {
        float4 r = *(const float4*)(res + i4);
        a.x += r.x; a.y += r.y; a.z += r.z; a.w += r.w;
    }
    *(float4*)(out + i4) = make_float4(a.x + bb, a.y + bb, a.z + bb, a.w + bb);
}

// ================= PAC gaussian ================================================
__global__ __launch_bounds__(256) void pack_d(const float* __restrict__ g,
    float* __restrict__ part, int Cg, int CS, int H, int W, int NS, size_t SS)
{
    int z = blockIdx.y;
    int b = z / NS, sl = z - b * NS;
    int p = blockIdx.x * 256 + threadIdx.x;
    int y = p / W, x = p - y * W;
    float acc[9];
    #pragma unroll
    for (int t = 0; t < 9; t++) acc[t] = 0.f;
    const float* gb = g + ((size_t)b * Cg + sl * CS) * H * W;
    for (int ci = 0; ci < CS; ci++) {
        const float* gc = gb + (size_t)ci * H * W;
        float ctr = gc[p];
        #pragma unroll
        for (int i = 0; i < 3; i++) {
            int yy = y + i - 1;
            bool yok = (yy >= 0 && yy < H);
            #pragma unroll
            for (int j = 0; j < 3; j++) {
                int xx = x + j - 1;
                float nb = (yok && xx >= 0 && xx < W) ? gc[yy * W + xx] : 0.f;
                float d = nb - ctr;
                acc[i * 3 + j] = fmaf(d, d, acc[i * 3 + j]);
            }
        }
    }
    size_t HW = (size_t)H * W;
    #pragma unroll
    for (int t = 0; t < 9; t++)
        part[(size_t)sl * SS + ((size_t)b * 9 + t) * HW + p] = acc[t];
}

__global__ __launch_bounds__(256) void expcomb_k(const float* __restrict__ part,
    float* __restrict__ K, int NS, size_t SS)
{
    int i4 = (blockIdx.x * 256 + threadIdx.x) * 4;
    float4 a = make_float4(0.f, 0.f, 0.f, 0.f);
    for (int s = 0; s < NS; s++) {
        float4 p = *(const float4*)(part + (size_t)s * SS + i4);
        a.x += p.x; a.y += p.y; a.z += p.z; a.w += p.w;
    }
    *(float4*)(K + i4) = make_float4(expf(-0.5f * a.x), expf(-0.5f * a.y),
                                     expf(-0.5f * a.z), expf(-0.5f * a.w));
}

// ================= PacConvT stage B: scatter/gather ============================
template<int NCO>
__global__ __launch_bounds__(256) void pacsc_k(const float* __restrict__ Gin,
    const float* __restrict__ K, const float* __restrict__ bias,
    float* __restrict__ out, int Cout, int Hi, int Wi, size_t gstride)
{
    int b = blockIdx.z;
    int H = Hi << 1, W = Wi << 1;
    int HW = H * W, HWi = Hi * Wi, WC = W >> 2;
    int idx = blockIdx.x * 256 + threadIdx.x;
    int half = (H >> 1) * WC;
    int py = (idx >= half) ? 1 : 0;
    int r = idx - py * half;
    int ry = r / WC;
    int y = 2 * ry + py;
    int x0 = (r - ry * WC) << 2;
    int yi = y >> 1, xi0 = x0 >> 1;
    int co0 = blockIdx.y * NCO;
    const float* G  = Gin + (size_t)b * gstride;
    const float* Kb = K + (size_t)b * 9 * HW;
    float* ob = out + (size_t)b * Cout * HW;
    size_t krow = (size_t)y * W + x0;
    bool vok = (xi0 + 2 < Wi);

    if (py == 0) {
        float k4a = Kb[(size_t)4 * HW + krow],     k4b = Kb[(size_t)4 * HW + krow + 2];
        float k3a = Kb[(size_t)3 * HW + krow + 1], k3b = Kb[(size_t)3 * HW + krow + 3];
        float k5a = Kb[(size_t)5 * HW + krow + 1], k5b = Kb[(size_t)5 * HW + krow + 3];
        #pragma unroll
        for (int j = 0; j < NCO; j++) {
            int co = co0 + j;
            size_t rowb = (size_t)yi * Wi + xi0;
            const float* g3 = G + (size_t)(3 * Cout + co) * HWi + rowb;
            const float* g4 = G + (size_t)(4 * Cout + co) * HWi + rowb;
            const float* g5 = G + (size_t)(5 * Cout + co) * HWi + rowb;
            float bb = bias[co];
            float g5b = vok ? g5[2] : 0.f;
            float o0 = fmaf(k4a, g4[0], bb);
            float o1 = fmaf(k3a, g3[0], fmaf(k5a, g5[1], bb));
            float o2 = fmaf(k4b, g4[1], bb);
            float o3 = fmaf(k3b, g3[1], fmaf(k5b, g5b, bb));
            *(float4*)(ob + (size_t)co * HW + krow) = make_float4(o0, o1, o2, o3);
        }
    } else {
        bool yok = (yi + 1 < Hi);
        float k1a = Kb[(size_t)1 * HW + krow],     k1b = Kb[(size_t)1 * HW + krow + 2];
        float k7a = Kb[(size_t)7 * HW + krow],     k7b = Kb[(size_t)7 * HW + krow + 2];
        float k0a = Kb[(size_t)0 * HW + krow + 1], k0b = Kb[(size_t)0 * HW + krow + 3];
        float k2a = Kb[(size_t)2 * HW + krow + 1], k2b = Kb[(size_t)2 * HW + krow + 3];
        float k6a = Kb[(size_t)6 * HW + krow + 1], k6b = Kb[(size_t)6 * HW + krow + 3];
        float k8a = Kb[(size_t)8 * HW + krow + 1], k8b = Kb[(size_t)8 * HW + krow + 3];
        #pragma unroll
        for (int j = 0; j < NCO; j++) {
            int co = co0 + j;
            size_t row0 = (size_t)yi * Wi + xi0;
            size_t row1 = (size_t)(yi + 1) * Wi + xi0;
            const float* g0 = G + (size_t)(0 * Cout + co) * HWi + row0;
            const float* g1 = G + (size_t)(1 * Cout + co) * HWi + row0;
            const float* g2 = G + (size_t)(2 * Cout + co) * HWi + row0;
            const float* g6 = G + (size_t)(6 * Cout + co) * HWi + row1;
            const float* g7 = G + (size_t)(7 * Cout + co) * HWi + row1;
            const float* g8 = G + (size_t)(8 * Cout + co) * HWi + row1;
            float bb = bias[co];
            float g2b = vok ? g2[2] : 0.f;
            float g6a = yok ? g6[0] : 0.f, g6b = yok ? g6[1] : 0.f;
            float g7a = yok ? g7[0] : 0.f, g7b = yok ? g7[1] : 0.f;
            float g8a = yok ? g8[1] : 0.f;
            float g8b = (yok && vok) ? g8[2] : 0.f;
            float o0 = fmaf(k1a, g1[0], fmaf(k7a, g7a, bb));
            float o1 = fmaf(k0a, g0[0], fmaf(k2a, g2[1],
                       fmaf(k6a, g6a, fmaf(k8a, g8a, bb))));
            float o2 = fmaf(k1b, g1[1], fmaf(k7b, g7b, bb));
            float o3 = fmaf(k0b, g0[1], fmaf(k2b, g2b,
                       fmaf(k6b, g6b, fmaf(k8b, g8b, bb))));
            *(float4*)(ob + (size_t)co * HW + krow) = make_float4(o0, o1, o2, o3);
        }
    }
}

// ==============================================================================
extern "C" void kernel_launch(void* const* d_in, const int* in_sizes, int n_in,
                              void* d_out, int out_size, void* d_ws, size_t ws_size,
                              hipStream_t stream)
{
    const float* x   = (const float*)d_in[0];   // (2,256,64,64)
    const float* ef2 = (const float*)d_in[1];   // (2,64,128,128)
    const float* ef1 = (const float*)d_in[2];   // (2,32,256,256)
    const float* Wd  = (const float*)d_in[3];
    const float* bd  = (const float*)d_in[4];
    const float* Wm  = (const float*)d_in[5];
    const float* bm  = (const float*)d_in[6];
    const float* Wa2 = (const float*)d_in[7];
    const float* ba2 = (const float*)d_in[8];
    const float* Wa1 = (const float*)d_in[9];
    const float* ba1 = (const float*)d_in[10];
    const float* W16 = (const float*)d_in[11];
    const float* b16 = (const float*)d_in[12];
    const float* W20 = (const float*)d_in[13];
    const float* b20 = (const float*)d_in[14];
    const float* W24 = (const float*)d_in[15];
    const float* b24 = (const float*)d_in[16];
    float* out = (float*)d_out;                 // (2,3,256,256)

    // ---- workspace regions (floats), identical to R5's 449us layout ----
    float* A = (float*)d_ws;        // 8,388,608
    float* B = A + 8388608;         // 4,194,304
    float* C = B + 4194304;         // 2,097,152: t0 / x3
    float* D = C + 2097152;         // 1,048,576: x1 / x2
    float* E = D + 1048576;         //   294,912: K2
    float* Hh = E + 294912;         //    93,568: wT1b/wT2b bf16 + stats

    float* t0 = C;  float* x3 = C;
    float* x1 = D;  float* x2 = D;
    float* g2 = B;  float* x5 = B;
    float* g1 = A;
    float* Gin = A;                       // A0: up to 4,718,592
    float* K1  = A + 4718592;             // 1,179,648
    float* K2  = E;

    ushort* padDb  = (ushort*)A;                  // 2,230,272 us (step 2)
    ushort* wbD    = (ushort*)(A + 1115136);      //   294,912 us
    float*  Pd     = A + 1262592;                 // 4x1,048,576 fl
    ushort* padA2b = (ushort*)A;                  // 2,163,200 us (step 4)
    ushort* wbA2b  = (ushort*)(A + 1081600);      //    73,728 us
    ushort* padA1b = (ushort*)B;                  // 4,260,096 us (step 8)
    ushort* wbA1b  = (ushort*)(B + 2130048);      //    18,432 us
    ushort* x2b    = (ushort*)(A + 4718592);      // 1,048,576 us (step 6)
    ushort* x3b    = (ushort*)(A + 5898240);      // 2,097,152 us (step 10)
    ushort* wT1b   = (ushort*)Hh;                 //    73,728 us
    ushort* wT2b   = (ushort*)(Hh + 36864);       //    18,432 us
    float*  ST     = Hh + 46080;                  //     1,408
    float* st0 = ST; float* st3 = ST + 1024; float* st5 = ST + 1280;

    wtb2_k<<<dim3(288), dim3(256), 0, stream>>>(W16, wT1b, 128, 64, 73728);
    wtb2_k<<<dim3(72),  dim3(256), 0, stream>>>(W20, wT2b, 64, 32, 18432);

    // 1) inorm(x) -> t0  (stable deterministic stats)
    istat2_k<<<dim3(512), dim3(256), 0, stream>>>(x, st0, 4096);
    iapply_k<<<dim3(2048), dim3(256), 0, stream>>>(x, st0, t0, 4096, 0);

    // 2) conv_down 256->128 @64x64 via MFMA (K-split 4) -> Pd; reduce -> x1
    pad_k<<<dim3(1089, 2), dim3(256), 0, stream>>>(t0, padDb, 256, 64, 64, 1, 278784);
    wtb_k<<<dim3(1152), dim3(256), 0, stream>>>(Wd, wbD, 256, 294912);
    mg2_k<256, 9, 2><<<dim3(64, 2, 8), dim3(256), 0, stream>>>(
        padDb, wbD, nullptr, Pd, 6, 66, 4, 64, 1, (size_t)1048576,
        (size_t)1115136, (size_t)524288, 4096);
    reduce_k<<<dim3(1024), dim3(256), 0, stream>>>(Pd, bd, nullptr, x1, 4096, 128, 4, 1048576);

    // 3) 1x1 fp32: NS=8 -> P(A); reduce + residual -> x2
    conv1x1_d<8><<<dim3(4, 16, 16), dim3(256), 0, stream>>>(
        x1, Wm, A, 128, 16, 4096, 8, (size_t)1048576);
    reduce_k<<<dim3(1024), dim3(256), 0, stream>>>(A, bm, x1, x2, 4096, 128, 8, 1048576);

    // 4) adjust_ef_lv2 64->128 @128x128 MFMA -> g2
    pad_k<<<dim3(1057, 2), dim3(256), 0, stream>>>(ef2, padA2b, 64, 128, 128, 1, 270400);
    wtb_k<<<dim3(288), dim3(256), 0, stream>>>(Wa2, wbA2b, 64, 73728);
    mg2_k<64, 9, 2><<<dim3(256, 2, 2), dim3(256), 0, stream>>>(
        padA2b, wbA2b, ba2, g2, 7, 130, 1, 64, 1, (size_t)0,
        (size_t)1081600, (size_t)2097152, 16384);

    // 5) PAC kernel K2: NS=8 -> P(A); exp-combine -> K2
    pack_d<<<dim3(64, 16), dim3(256), 0, stream>>>(g2, A, 128, 16, 128, 128, 8, (size_t)294912);
    expcomb_k<<<dim3(288), dim3(256), 0, stream>>>(A, K2, 8, 294912);

    // 6) PacConvT #1: stage x2 -> bf16; MFMA GEMM (N=576) -> Gin; scatter -> x3
    pad_k<<<dim3(512, 2), dim3(256), 0, stream>>>(x2, x2b, 128, 64, 64, 0, 131072);
    mg2_k<128, 1, 2><<<dim3(64, 9, 2), dim3(256), 0, stream>>>(
        x2b, wT1b, nullptr, Gin, 6, 0, 1, 128, 2, (size_t)0,
        (size_t)524288, (size_t)2359296, 4096);
    pacsc_k<2><<<dim3(16, 32, 2), dim3(256), 0, stream>>>(
        Gin, K2, b16, x3, 64, 64, 64, (size_t)2359296);

    // 7) double inorm+res: x3 = x3 + 2*inorm(x3)
    istat2_k<<<dim3(128), dim3(256), 0, stream>>>(x3, st3, 16384);
    iapply_k<<<dim3(2048), dim3(256), 0, stream>>>(x3, st3, x3, 16384, 2);

    // 8) adjust_ef_lv1 32->64 @256x256 MFMA -> g1(A)
    pad_k<<<dim3(2081, 2), dim3(256), 0, stream>>>(ef1, padA1b, 32, 256, 256, 1, 532512);
    wtb_k<<<dim3(72), dim3(256), 0, stream>>>(Wa1, wbA1b, 32, 18432);
    mg2_k<32, 9, 2><<<dim3(1024, 1, 2), dim3(256), 0, stream>>>(
        padA1b, wbA1b, ba1, g1, 8, 258, 1, 32, 0, (size_t)0,
        (size_t)2130048, (size_t)4194304, 65536);

    // 9) PAC kernel K1: NS=2 -> P(B); exp-combine -> K1(A-tail)
    pack_d<<<dim3(256, 4), dim3(256), 0, stream>>>(g1, B, 64, 32, 256, 256, 2, (size_t)1179648);
    expcomb_k<<<dim3(1152), dim3(256), 0, stream>>>(B, K1, 2, 1179648);

    // 10) PacConvT #2: stage x3 -> bf16 (both b); per-batch MFMA GEMM + scatter
    pad_k<<<dim3(1024, 2), dim3(256), 0, stream>>>(x3, x3b, 64, 128, 128, 0, 262144);
    for (int b = 0; b < 2; b++) {
        mg2_k<64, 1, 1><<<dim3(128, 9, 1), dim3(256), 0, stream>>>(
            x3b + (size_t)b * 1048576, wT2b, nullptr, Gin, 7, 0, 1, 64, 1,
            (size_t)0, (size_t)0, (size_t)0, 16384);
        pacsc_k<2><<<dim3(64, 16, 1), dim3(256), 0, stream>>>(
            Gin, K1 + (size_t)b * 9 * 65536, b20, x5 + (size_t)b * 32 * 65536,
            32, 128, 128, (size_t)0);
    }

    // 11) double inorm+res on x5
    istat2_k<<<dim3(64), dim3(256), 0, stream>>>(x5, st5, 65536);
    iapply_k<<<dim3(4096), dim3(256), 0, stream>>>(x5, st5, x5, 65536, 2);

    // 12) final 32->3 @256x256 fp32: NS=4 -> P(A); reduce -> out
    conv3x3_d<3><<<dim3(64, 1, 8), dim3(256), 0, stream>>>(
        x5, W24, nullptr, A, 32, 8, 256, 256, 3, 4, (size_t)393216);
    reduce_k<<<dim3(384), dim3(256), 0, stream>>>(A, b24, nullptr, out, 65536, 3, 4, 393216);
}

// Round 10
// 440.075 us; speedup vs baseline: 1.0438x; 1.0438x over previous
//
#include <hip/hip_runtime.h>

#define EPS 1e-5f

typedef short sh8 __attribute__((ext_vector_type(8)));    // 8 x bf16 (4 VGPR)
typedef float f32x4 __attribute__((ext_vector_type(4)));  // MFMA acc frag

__device__ __forceinline__ ushort f2b(float f) {
    unsigned u = __float_as_uint(f);
    u += 0x7fffu + ((u >> 16) & 1u);          // RNE
    return (ushort)(u >> 16);
}

// ====== InstanceNorm stats: DETERMINISTIC + STABLE (two-phase, 1 blk/chan) =====
// st[2ch]=mean, st[2ch+1]=var (stable sum((v-m)^2) form — E[x^2]-m^2 cancels)
__global__ __launch_bounds__(256) void istat2_k(const float* __restrict__ in,
                                                float* st, int HW)
{
    __shared__ float sh[256];
    int ch = blockIdx.x;
    const float* p = in + (size_t)ch * HW;
    float s = 0.f;
    for (int i = threadIdx.x * 4; i < HW; i += 1024) {
        float4 v = *(const float4*)(p + i);
        s += v.x + v.y + v.z + v.w;
    }
    sh[threadIdx.x] = s;
    __syncthreads();
    for (int o = 128; o > 0; o >>= 1) {
        if ((int)threadIdx.x < o) sh[threadIdx.x] += sh[threadIdx.x + o];
        __syncthreads();
    }
    float m = sh[0] / (float)HW;
    __syncthreads();
    float s2 = 0.f;
    for (int i = threadIdx.x * 4; i < HW; i += 1024) {
        float4 v = *(const float4*)(p + i);
        float d0 = v.x - m, d1 = v.y - m, d2 = v.z - m, d3 = v.w - m;
        s2 += d0 * d0 + d1 * d1 + d2 * d2 + d3 * d3;
    }
    sh[threadIdx.x] = s2;
    __syncthreads();
    for (int o = 128; o > 0; o >>= 1) {
        if ((int)threadIdx.x < o) sh[threadIdx.x] += sh[threadIdx.x + o];
        __syncthreads();
    }
    if (threadIdx.x == 0) {
        st[2 * ch]     = m;
        st[2 * ch + 1] = sh[0] / (float)HW;
    }
}

// apply (mode 0: r, mode 2: v+2r); st holds (mean, var)
__global__ __launch_bounds__(256) void iapply_k(const float* in, const float* st,
                                                float* out, int HW, int mode)
{
    int i4 = (blockIdx.x * 256 + threadIdx.x) * 4;
    int ch = i4 / HW;
    float m = st[2 * ch];
    float inv = rsqrtf(st[2 * ch + 1] + EPS);
    float4 v = *(const float4*)(in + i4);
    float4 r;
    r.x = (v.x - m) * inv; r.y = (v.y - m) * inv;
    r.z = (v.z - m) * inv; r.w = (v.w - m) * inv;
    if (mode == 2) {
        r.x = v.x + 2.f * r.x; r.y = v.y + 2.f * r.y;
        r.z = v.z + 2.f * r.z; r.w = v.w + 2.f * r.w;
    }
    *(float4*)(out + i4) = r;
}

// fused inorm-apply (mode0) + padded NHWC bf16 stage; st=(mean,var)
__global__ __launch_bounds__(256) void ipad_k(const float* __restrict__ in,
    const float* __restrict__ st, ushort* __restrict__ ob,
    int C, int H, int W, int pad, int n4)
{
    int idx = blockIdx.x * 256 + threadIdx.x;
    if (idx >= n4) return;
    int b = blockIdx.y;
    int cpp = C >> 2;
    int pp = idx / cpp, c0 = (idx - pp * cpp) * 4;
    int Wp = W + 2 * pad, Hp = H + 2 * pad;
    int yp = pp / Wp, xp = pp - yp * Wp;
    int y = yp - pad, x = xp - pad;
    ushort4 o;
    if (y >= 0 && y < H && x >= 0 && x < W) {
        size_t HW = (size_t)H * W;
        const float* ib = in + (size_t)b * C * HW + (size_t)y * W + x;
        #pragma unroll
        for (int u = 0; u < 4; u++) {
            int chg = b * C + c0 + u;
            float m = st[2 * chg];
            float inv = rsqrtf(st[2 * chg + 1] + EPS);
            float v = ib[(size_t)(c0 + u) * HW];
            ((ushort*)&o)[u] = f2b((v - m) * inv);
        }
    } else { o.x = o.y = o.z = o.w = 0; }
    *(ushort4*)(ob + ((size_t)b * Hp * Wp + pp) * C + c0) = o;
}

// fused inorm-apply (mode2: v+2r) -> NHWC bf16 (no pad); st=(mean,var)
__global__ __launch_bounds__(256) void iapad_k(const float* __restrict__ in,
    const float* __restrict__ st, ushort* __restrict__ ob, int HW, int Co)
{
    int i4 = (blockIdx.x * 256 + threadIdx.x) * 4;
    int ch = i4 / HW;
    int p = i4 - ch * HW;
    int b = ch / Co, c = ch - b * Co;
    float m = st[2 * ch];
    float inv = rsqrtf(st[2 * ch + 1] + EPS);
    float4 v = *(const float4*)(in + i4);
    ushort* op = ob + ((size_t)b * HW + p) * Co + c;
    op[0]              = f2b(v.x + 2.f * (v.x - m) * inv);
    op[(size_t)Co]     = f2b(v.y + 2.f * (v.y - m) * inv);
    op[(size_t)Co * 2] = f2b(v.z + 2.f * (v.z - m) * inv);
    op[(size_t)Co * 3] = f2b(v.w + 2.f * (v.w - m) * inv);
}

// ================= plain NCHW f32 -> (padded) NHWC bf16 ========================
__global__ __launch_bounds__(256) void pad_k(const float* __restrict__ in,
    ushort* __restrict__ ob, int C, int H, int W, int pad, int n4)
{
    int idx = blockIdx.x * 256 + threadIdx.x;
    if (idx >= n4) return;
    int b = blockIdx.y;
    int cpp = C >> 2;
    int pp = idx / cpp, c0 = (idx - pp * cpp) * 4;
    int Wp = W + 2 * pad, Hp = H + 2 * pad;
    int yp = pp / Wp, xp = pp - yp * Wp;
    int y = yp - pad, x = xp - pad;
    ushort4 o;
    if (y >= 0 && y < H && x >= 0 && x < W) {
        const float* ib = in + ((size_t)b * C) * H * W + (size_t)y * W + x;
        size_t HW = (size_t)H * W;
        o.x = f2b(ib[(size_t)(c0    ) * HW]);
        o.y = f2b(ib[(size_t)(c0 + 1) * HW]);
        o.z = f2b(ib[(size_t)(c0 + 2) * HW]);
        o.w = f2b(ib[(size_t)(c0 + 3) * HW]);
    } else { o.x = o.y = o.z = o.w = 0; }
    *(ushort4*)(ob + ((size_t)b * Hp * Wp + pp) * C + c0) = o;
}

// ================= fused weight prep (all bf16 layers, one kernel) =============
__global__ __launch_bounds__(256) void wprep_k(
    const float* W16, const float* W20, const float* Wd, const float* Wa2,
    const float* Wa1,
    ushort* wT1b, ushort* wT2b, ushort* wbD, ushort* wbA2b, ushort* wbA1b)
{
    int idx = blockIdx.x * 256 + threadIdx.x;
    if (idx < 73728) {                       // wT1b: convT (128,64) -> [t*64+o][ci]
        int to = idx / 128, ci = idx - to * 128;
        int t = to / 64, o = to - t * 64;
        wT1b[idx] = f2b(W16[((size_t)ci * 64 + o) * 9 + t]);
        return;
    } idx -= 73728;
    if (idx < 18432) {                       // wT2b: convT (64,32)
        int to = idx / 64, ci = idx - to * 64;
        int t = to / 32, o = to - t * 32;
        wT2b[idx] = f2b(W20[((size_t)ci * 32 + o) * 9 + t]);
        return;
    } idx -= 18432;
    if (idx < 294912) {                      // wbD: OIHW(128,256) -> [co][t][ci]
        int co = idx / 2304, r = idx - co * 2304;
        int t = r / 256, ci = r - t * 256;
        wbD[idx] = f2b(Wd[((size_t)co * 256 + ci) * 9 + t]);
        return;
    } idx -= 294912;
    if (idx < 73728) {                       // wbA2b: OIHW(128,64)
        int co = idx / 576, r = idx - co * 576;
        int t = r / 64, ci = r - t * 64;
        wbA2b[idx] = f2b(Wa2[((size_t)co * 64 + ci) * 9 + t]);
        return;
    } idx -= 73728;
    if (idx < 18432) {                       // wbA1b: OIHW(64,32)
        int co = idx / 288, r = idx - co * 288;
        int t = r / 32, ci = r - t * 32;
        wbA1b[idx] = f2b(Wa1[((size_t)co * 32 + ci) * 9 + t]);
        return;
    }
}

// ================= MFMA GEMM v2: reg-tiled 2x2, software-pipelined =============
// wave: 32 px x 32 n; NWX=2: block 64px x 64n; NWX=1: 128px x 32n
template<int CI, int TAPS, int NWX>
__global__ __launch_bounds__(256) void mg2_k(
    const ushort* __restrict__ inb, const ushort* __restrict__ wb,
    const float* __restrict__ bias, float* __restrict__ outp,
    int wshift, int Wp, int NS, int CSL, int nchs, size_t SS,
    size_t in_bstride, size_t out_bstride, int HW)
{
    int z = blockIdx.z;
    int b = z / NS, sl = z - b * NS;
    int cilo = sl * CSL;
    int tid = threadIdx.x;
    int wv = tid >> 6, l = tid & 63;
    int lane16 = l & 15, quad = l >> 4;
    int klane = quad * 8;
    int wy, wx;
    if (NWX == 2) { wy = wv & 1; wx = wv >> 1; }
    else          { wy = wv;     wx = 0; }
    const int PXB = (NWX == 2) ? 64 : 128;
    int pb = blockIdx.x * PXB + wy * 32;
    int nb = blockIdx.y * (NWX * 32) + wx * 32;

    int base[2];
    #pragma unroll
    for (int i = 0; i < 2; i++) {
        int pm = pb + i * 16 + lane16;
        if (TAPS == 9) {
            int W = 1 << wshift;
            int y = pm >> wshift, xx = pm & (W - 1);
            base[i] = (y + 1) * Wp + (xx + 1);
        } else base[i] = pm;
    }
    int nn[2];
    nn[0] = nb + lane16; nn[1] = nb + 16 + lane16;

    const ushort* inbb = inb + (size_t)b * in_bstride + cilo + klane;
    const ushort* wbb  = wb + cilo + klane;

    f32x4 vz = {0.f, 0.f, 0.f, 0.f};
    f32x4 acc[2][2] = {{vz, vz}, {vz, vz}};
    sh8 a[2], bf[2], an[2], bn[2];
    int totk = TAPS << nchs;

    #define LDK(kk, av, bv) { \
        int t_ = (kk) >> nchs, c_ = (kk) - (t_ << nchs); \
        int dof_ = 0; \
        if (TAPS == 9) { \
            int dy_ = (t_ * 43) >> 7; \
            int dx_ = t_ - dy_ * 3; \
            dof_ = (dy_ - 1) * Wp + (dx_ - 1); \
        } \
        int coff_ = c_ << 5; \
        av[0] = *(const sh8*)(inbb + (size_t)(base[0] + dof_) * CI + coff_); \
        av[1] = *(const sh8*)(inbb + (size_t)(base[1] + dof_) * CI + coff_); \
        bv[0] = *(const sh8*)(wbb + ((size_t)nn[0] * TAPS + t_) * CI + coff_); \
        bv[1] = *(const sh8*)(wbb + ((size_t)nn[1] * TAPS + t_) * CI + coff_); \
    }

    LDK(0, a, bf)
    for (int kk = 0; kk < totk; kk++) {
        if (kk + 1 < totk) LDK(kk + 1, an, bn)
        acc[0][0] = __builtin_amdgcn_mfma_f32_16x16x32_bf16(a[0], bf[0], acc[0][0], 0, 0, 0);
        acc[0][1] = __builtin_amdgcn_mfma_f32_16x16x32_bf16(a[0], bf[1], acc[0][1], 0, 0, 0);
        acc[1][0] = __builtin_amdgcn_mfma_f32_16x16x32_bf16(a[1], bf[0], acc[1][0], 0, 0, 0);
        acc[1][1] = __builtin_amdgcn_mfma_f32_16x16x32_bf16(a[1], bf[1], acc[1][1], 0, 0, 0);
        a[0] = an[0]; a[1] = an[1]; bf[0] = bn[0]; bf[1] = bn[1];
    }
    #undef LDK

    float* ob = outp + (size_t)sl * SS + (size_t)b * out_bstride;
    #pragma unroll
    for (int j = 0; j < 2; j++) {
        float bb = bias ? bias[nn[j]] : 0.f;
        #pragma unroll
        for (int i = 0; i < 2; i++) {
            int p0 = pb + i * 16 + quad * 4;
            *(float4*)(ob + (size_t)nn[j] * HW + p0) =
                make_float4(acc[i][j][0] + bb, acc[i][j][1] + bb,
                            acc[i][j][2] + bb, acc[i][j][3] + bb);
        }
    }
}

// ================= Direct 3x3 conv fp32 (final 32->3) ==========================
template<int NCO>
__global__ __launch_bounds__(256) void conv3x3_d(const float* __restrict__ in,
    const float* __restrict__ w, const float* __restrict__ bias,
    float* __restrict__ outp, int Ci, int CS, int H, int W, int Co, int NS,
    size_t SS)
{
    int z = blockIdx.z;
    int b = z / NS, sl = z - b * NS;
    int WC = W >> 2;
    int idx = blockIdx.x * 256 + threadIdx.x;
    int xc = idx % WC, y = idx / WC;
    int x0 = xc << 2;
    bool lz = (x0 == 0), rz = (x0 + 4 == W);
    int co0 = blockIdx.y * NCO;
    float acc[NCO][4];
    #pragma unroll
    for (int j = 0; j < NCO; j++)
        #pragma unroll
        for (int p = 0; p < 4; p++) acc[j][p] = 0.f;

    const float* ib = in + ((size_t)b * Ci + sl * CS) * H * W;
    for (int ci = 0; ci < CS; ci++) {
        const float* ic = ib + (size_t)ci * H * W;
        float e[3][6];
        #pragma unroll
        for (int r = 0; r < 3; r++) {
            int yy = y + r - 1;
            float4 v = make_float4(0.f, 0.f, 0.f, 0.f);
            if (yy >= 0 && yy < H)
                v = *(const float4*)(ic + (size_t)yy * W + x0);
            float lf = __shfl_up(v.w, 1);
            float rt = __shfl_down(v.x, 1);
            e[r][0] = lz ? 0.f : lf;
            e[r][1] = v.x; e[r][2] = v.y; e[r][3] = v.z; e[r][4] = v.w;
            e[r][5] = rz ? 0.f : rt;
        }
        int cig = sl * CS + ci;
        #pragma unroll
        for (int j = 0; j < NCO; j++) {
            const float* wj = w + ((size_t)(co0 + j) * Ci + cig) * 9;
            #pragma unroll
            for (int r = 0; r < 3; r++) {
                float w0 = wj[3 * r], w1 = wj[3 * r + 1], w2 = wj[3 * r + 2];
                #pragma unroll
                for (int p = 0; p < 4; p++)
                    acc[j][p] = fmaf(e[r][p], w0,
                                fmaf(e[r][p + 1], w1,
                                fmaf(e[r][p + 2], w2, acc[j][p])));
            }
        }
    }
    size_t HW = (size_t)H * W;
    #pragma unroll
    for (int j = 0; j < NCO; j++) {
        float bb = bias ? bias[co0 + j] : 0.f;
        float4 o = make_float4(acc[j][0] + bb, acc[j][1] + bb,
                               acc[j][2] + bb, acc[j][3] + bb);
        float* op = outp + (size_t)sl * SS
                  + ((size_t)b * Co + co0 + j) * HW + (size_t)y * W + x0;
        *(float4*)op = o;
    }
}

// ================= Direct 1x1 conv fp32 (precision-critical) ===================
template<int NCO>
__global__ __launch_bounds__(256) void conv1x1_d(const float* __restrict__ in,
    const float* __restrict__ w, float* __restrict__ outp,
    int C, int CS, int HW, int NS, size_t SS)
{
    int z = blockIdx.z;
    int b = z / NS, sl = z - b * NS;
    int x0 = (blockIdx.x * 256 + threadIdx.x) * 4;
    int co0 = blockIdx.y * NCO;
    float acc[NCO][4];
    #pragma unroll
    for (int j = 0; j < NCO; j++)
        #pragma unroll
        for (int p = 0; p < 4; p++) acc[j][p] = 0.f;
    const float* ib = in + ((size_t)b * C + sl * CS) * HW;
    for (int ci = 0; ci < CS; ci++) {
        float4 v = *(const float4*)(ib + (size_t)ci * HW + x0);
        int cig = sl * CS + ci;
        #pragma unroll
        for (int j = 0; j < NCO; j++) {
            float wv = w[(size_t)(co0 + j) * C + cig];
            acc[j][0] = fmaf(v.x, wv, acc[j][0]);
            acc[j][1] = fmaf(v.y, wv, acc[j][1]);
            acc[j][2] = fmaf(v.z, wv, acc[j][2]);
            acc[j][3] = fmaf(v.w, wv, acc[j][3]);
        }
    }
    #pragma unroll
    for (int j = 0; j < NCO; j++) {
        float* op = outp + (size_t)sl * SS + ((size_t)b * C + co0 + j) * HW + x0;
        *(float4*)op = make_float4(acc[j][0], acc[j][1], acc[j][2], acc[j][3]);
    }
}

// ================= reduce partials (+bias, optional residual) ==================
__global__ __launch_bounds__(256) void reduce_k(const float* __restrict__ part,
    const float* __restrict__ bias, const float* res, float* out,
    int HW, int Co, int NS, size_t SS)
{
    int i4 = (blockIdx.x * 256 + threadIdx.x) * 4;
    float4 a = make_float4(0.f, 0.f, 0.f, 0.f);
    for (int s = 0; s < NS; s++) {
        float4 p = *(const float4*)(part + (size_t)s * SS + i4);
        a.x += p.x; a.y += p.y; a.z += p.z; a.w += p.w;
    }
    int c = (i4 / HW) % Co;
    float bb = bias[c];
    if (res) {
        float4 r = *(const float4*)(res + i4);
        a.x += r.x; a.y += r.y; a.z += r.z; a.w += r.w;
    }
    *(float4*)(out + i4) = make_float4(a.x + bb, a.y + bb, a.z + bb, a.w + bb);
}

// ================= PAC gaussian (NS=1: fused exp; else partial) ================
__global__ __launch_bounds__(256) void pack_d(const float* __restrict__ g,
    float* __restrict__ part, int Cg, int CS, int H, int W, int NS, size_t SS)
{
    int z = blockIdx.y;
    int b = z / NS, sl = z - b * NS;
    int p = blockIdx.x * 256 + threadIdx.x;
    int y = p / W, x = p - y * W;
    float acc[9];
    #pragma unroll
    for (int t = 0; t < 9; t++) acc[t] = 0.f;
    const float* gb = g + ((size_t)b * Cg + sl * CS) * H * W;
    for (int ci = 0; ci < CS; ci++) {
        const float* gc = gb + (size_t)ci * H * W;
        float ctr = gc[p];
        #pragma unroll
        for (int i = 0; i < 3; i++) {
            int yy = y + i - 1;
            bool yok = (yy >= 0 && yy < H);
            #pragma unroll
            for (int j = 0; j < 3; j++) {
                int xx = x + j - 1;
                float nb = (yok && xx >= 0 && xx < W) ? gc[yy * W + xx] : 0.f;
                float d = nb - ctr;
                acc[i * 3 + j] = fmaf(d, d, acc[i * 3 + j]);
            }
        }
    }
    size_t HW = (size_t)H * W;
    #pragma unroll
    for (int t = 0; t < 9; t++) {
        float v = (NS == 1) ? expf(-0.5f * acc[t]) : acc[t];
        part[(size_t)sl * SS + ((size_t)b * 9 + t) * HW + p] = v;
    }
}

__global__ __launch_bounds__(256) void expcomb_k(const float* __restrict__ part,
    float* __restrict__ K, int NS, size_t SS)
{
    int i4 = (blockIdx.x * 256 + threadIdx.x) * 4;
    float4 a = make_float4(0.f, 0.f, 0.f, 0.f);
    for (int s = 0; s < NS; s++) {
        float4 p = *(const float4*)(part + (size_t)s * SS + i4);
        a.x += p.x; a.y += p.y; a.z += p.z; a.w += p.w;
    }
    *(float4*)(K + i4) = make_float4(expf(-0.5f * a.x), expf(-0.5f * a.y),
                                     expf(-0.5f * a.z), expf(-0.5f * a.w));
}

// ================= PacConvT stage B: scatter/gather ============================
template<int NCO>
__global__ __launch_bounds__(256) void pacsc_k(const float* __restrict__ Gin,
    const float* __restrict__ K, const float* __restrict__ bias,
    float* __restrict__ out, int Cout, int Hi, int Wi, size_t gstride)
{
    int b = blockIdx.z;
    int H = Hi << 1, W = Wi << 1;
    int HW = H * W, HWi = Hi * Wi, WC = W >> 2;
    int idx = blockIdx.x * 256 + threadIdx.x;
    int half = (H >> 1) * WC;
    int py = (idx >= half) ? 1 : 0;
    int r = idx - py * half;
    int ry = r / WC;
    int y = 2 * ry + py;
    int x0 = (r - ry * WC) << 2;
    int yi = y >> 1, xi0 = x0 >> 1;
    int co0 = blockIdx.y * NCO;
    const float* G  = Gin + (size_t)b * gstride;
    const float* Kb = K + (size_t)b * 9 * HW;
    float* ob = out + (size_t)b * Cout * HW;
    size_t krow = (size_t)y * W + x0;
    bool vok = (xi0 + 2 < Wi);

    if (py == 0) {
        float k4a = Kb[(size_t)4 * HW + krow],     k4b = Kb[(size_t)4 * HW + krow + 2];
        float k3a = Kb[(size_t)3 * HW + krow + 1], k3b = Kb[(size_t)3 * HW + krow + 3];
        float k5a = Kb[(size_t)5 * HW + krow + 1], k5b = Kb[(size_t)5 * HW + krow + 3];
        #pragma unroll
        for (int j = 0; j < NCO; j++) {
            int co = co0 + j;
            size_t rowb = (size_t)yi * Wi + xi0;
            const float* g3 = G + (size_t)(3 * Cout + co) * HWi + rowb;
            const float* g4 = G + (size_t)(4 * Cout + co) * HWi + rowb;
            const float* g5 = G + (size_t)(5 * Cout + co) * HWi + rowb;
            float bb = bias[co];
            float g5b = vok ? g5[2] : 0.f;
            float o0 = fmaf(k4a, g4[0], bb);
            float o1 = fmaf(k3a, g3[0], fmaf(k5a, g5[1], bb));
            float o2 = fmaf(k4b, g4[1], bb);
            float o3 = fmaf(k3b, g3[1], fmaf(k5b, g5b, bb));
            *(float4*)(ob + (size_t)co * HW + krow) = make_float4(o0, o1, o2, o3);
        }
    } else {
        bool yok = (yi + 1 < Hi);
        float k1a = Kb[(size_t)1 * HW + krow],     k1b = Kb[(size_t)1 * HW + krow + 2];
        float k7a = Kb[(size_t)7 * HW + krow],     k7b = Kb[(size_t)7 * HW + krow + 2];
        float k0a = Kb[(size_t)0 * HW + krow + 1], k0b = Kb[(size_t)0 * HW + krow + 3];
        float k2a = Kb[(size_t)2 * HW + krow + 1], k2b = Kb[(size_t)2 * HW + krow + 3];
        float k6a = Kb[(size_t)6 * HW + krow + 1], k6b = Kb[(size_t)6 * HW + krow + 3];
        float k8a = Kb[(size_t)8 * HW + krow + 1], k8b = Kb[(size_t)8 * HW + krow + 3];
        #pragma unroll
        for (int j = 0; j < NCO; j++) {
            int co = co0 + j;
            size_t row0 = (size_t)yi * Wi + xi0;
            size_t row1 = (size_t)(yi + 1) * Wi + xi0;
            const float* g0 = G + (size_t)(0 * Cout + co) * HWi + row0;
            const float* g1 = G + (size_t)(1 * Cout + co) * HWi + row0;
            const float* g2 = G + (size_t)(2 * Cout + co) * HWi + row0;
            const float* g6 = G + (size_t)(6 * Cout + co) * HWi + row1;
            const float* g7 = G + (size_t)(7 * Cout + co) * HWi + row1;
            const float* g8 = G + (size_t)(8 * Cout + co) * HWi + row1;
            float bb = bias[co];
            float g2b = vok ? g2[2] : 0.f;
            float g6a = yok ? g6[0] : 0.f, g6b = yok ? g6[1] : 0.f;
            float g7a = yok ? g7[0] : 0.f, g7b = yok ? g7[1] : 0.f;
            float g8a = yok ? g8[1] : 0.f;
            float g8b = (yok && vok) ? g8[2] : 0.f;
            float o0 = fmaf(k1a, g1[0], fmaf(k7a, g7a, bb));
            float o1 = fmaf(k0a, g0[0], fmaf(k2a, g2[1],
                       fmaf(k6a, g6a, fmaf(k8a, g8a, bb))));
            float o2 = fmaf(k1b, g1[1], fmaf(k7b, g7b, bb));
            float o3 = fmaf(k0b, g0[1], fmaf(k2b, g2b,
                       fmaf(k6b, g6b, fmaf(k8b, g8b, bb))));
            *(float4*)(ob + (size_t)co * HW + krow) = make_float4(o0, o1, o2, o3);
        }
    }
}

// ==============================================================================
extern "C" void kernel_launch(void* const* d_in, const int* in_sizes, int n_in,
                              void* d_out, int out_size, void* d_ws, size_t ws_size,
                              hipStream_t stream)
{
    const float* x   = (const float*)d_in[0];   // (2,256,64,64)
    const float* ef2 = (const float*)d_in[1];   // (2,64,128,128)
    const float* ef1 = (const float*)d_in[2];   // (2,32,256,256)
    const float* Wd  = (const float*)d_in[3];
    const float* bd  = (const float*)d_in[4];
    const float* Wm  = (const float*)d_in[5];
    const float* bm  = (const float*)d_in[6];
    const float* Wa2 = (const float*)d_in[7];
    const float* ba2 = (const float*)d_in[8];
    const float* Wa1 = (const float*)d_in[9];
    const float* ba1 = (const float*)d_in[10];
    const float* W16 = (const float*)d_in[11];
    const float* b16 = (const float*)d_in[12];
    const float* W20 = (const float*)d_in[13];
    const float* b20 = (const float*)d_in[14];
    const float* W24 = (const float*)d_in[15];
    const float* b24 = (const float*)d_in[16];
    float* out = (float*)d_out;                 // (2,3,256,256)

    // ---- linear no-alias workspace layout (floats); total ~212 MB of 256 MiB ----
    float* P = (float*)d_ws;
    size_t o = 0;
    auto take = [&](size_t n) { float* p = P + o; o += n; return p; };
    ushort* padDb  = (ushort*)take(1115136);   // 2x66x66x256 bf16
    ushort* wbD    = (ushort*)take(147456);
    float*  Pd     = take(4194304);            // conv_down partials NS=4
    float*  x1     = take(1048576);
    float*  Pm     = take(8388608);            // 1x1 partials NS=8
    float*  x2     = take(1048576);
    ushort* x2b    = (ushort*)take(524288);
    ushort* padA2b = (ushort*)take(1081600);   // 2x130x130x64
    ushort* wbA2b  = (ushort*)take(36864);
    float*  g2     = take(2097152);
    float*  PK2    = take(2359296);            // K2 partials NS=8
    float*  K2     = take(294912);
    float*  Gin1   = take(4718592);
    float*  x3     = take(2097152);
    ushort* x3b    = (ushort*)take(1048576);
    ushort* padA1b = (ushort*)take(2130048);   // 2x258x258x32
    ushort* wbA1b  = (ushort*)take(9216);
    float*  g1     = take(4194304);
    float*  K1     = take(1179648);
    float*  Gin2   = take(9437184);            // 2x288x16384
    float*  x5     = take(4194304);
    float*  Pf     = take(1572864);            // final conv partials NS=4
    ushort* wT1b   = (ushort*)take(36864);
    ushort* wT2b   = (ushort*)take(9216);
    float*  ST     = take(1408);
    float* st0 = ST; float* st3 = ST + 1024; float* st5 = ST + 1280;

    // 0) all bf16 weight preps (one kernel; 479,232 elems)
    wprep_k<<<dim3(1872), dim3(256), 0, stream>>>(
        W16, W20, Wd, Wa2, Wa1, wT1b, wT2b, wbD, wbA2b, wbA1b);

    // 1+2a) stable stats; fused inorm-apply + NHWC-bf16 pad -> padDb
    istat2_k<<<dim3(512), dim3(256), 0, stream>>>(x, st0, 4096);
    ipad_k<<<dim3(1089, 2), dim3(256), 0, stream>>>(x, st0, padDb, 256, 64, 64, 1, 278784);

    // 2b) conv_down 256->128 @64x64 MFMA (K-split 4) -> Pd; reduce -> x1
    mg2_k<256, 9, 2><<<dim3(64, 2, 8), dim3(256), 0, stream>>>(
        padDb, wbD, nullptr, Pd, 6, 66, 4, 64, 1, (size_t)1048576,
        (size_t)1115136, (size_t)524288, 4096);
    reduce_k<<<dim3(1024), dim3(256), 0, stream>>>(Pd, bd, nullptr, x1, 4096, 128, 4, 1048576);

    // 3) 1x1 fp32: NS=8 -> Pm; reduce + residual -> x2; bf16 stage
    conv1x1_d<8><<<dim3(4, 16, 16), dim3(256), 0, stream>>>(
        x1, Wm, Pm, 128, 16, 4096, 8, (size_t)1048576);
    reduce_k<<<dim3(1024), dim3(256), 0, stream>>>(Pm, bm, x1, x2, 4096, 128, 8, 1048576);
    pad_k<<<dim3(512, 2), dim3(256), 0, stream>>>(x2, x2b, 128, 64, 64, 0, 131072);

    // 4) adjust_ef_lv2 64->128 @128x128 MFMA -> g2
    pad_k<<<dim3(1057, 2), dim3(256), 0, stream>>>(ef2, padA2b, 64, 128, 128, 1, 270400);
    mg2_k<64, 9, 2><<<dim3(256, 2, 2), dim3(256), 0, stream>>>(
        padA2b, wbA2b, ba2, g2, 7, 130, 1, 64, 1, (size_t)0,
        (size_t)1081600, (size_t)2097152, 16384);

    // 5) PAC kernel K2: NS=8 -> PK2; exp-combine -> K2
    pack_d<<<dim3(64, 16), dim3(256), 0, stream>>>(g2, PK2, 128, 16, 128, 128, 8, (size_t)294912);
    expcomb_k<<<dim3(288), dim3(256), 0, stream>>>(PK2, K2, 8, 294912);

    // 6) PacConvT #1: MFMA GEMM (N=576) -> Gin1; scatter -> x3
    mg2_k<128, 1, 2><<<dim3(64, 9, 2), dim3(256), 0, stream>>>(
        x2b, wT1b, nullptr, Gin1, 6, 0, 1, 128, 2, (size_t)0,
        (size_t)524288, (size_t)2359296, 4096);
    pacsc_k<2><<<dim3(16, 32, 2), dim3(256), 0, stream>>>(
        Gin1, K2, b16, x3, 64, 64, 64, (size_t)2359296);

    // 7) double inorm+res fused into bf16-NHWC stage: x3b = bf16(x3 + 2*inorm(x3))
    istat2_k<<<dim3(128), dim3(256), 0, stream>>>(x3, st3, 16384);
    iapad_k<<<dim3(2048), dim3(256), 0, stream>>>(x3, st3, x3b, 16384, 64);

    // 8) adjust_ef_lv1 32->64 @256x256 MFMA -> g1
    pad_k<<<dim3(2081, 2), dim3(256), 0, stream>>>(ef1, padA1b, 32, 256, 256, 1, 532512);
    mg2_k<32, 9, 2><<<dim3(1024, 1, 2), dim3(256), 0, stream>>>(
        padA1b, wbA1b, ba1, g1, 8, 258, 1, 32, 0, (size_t)0,
        (size_t)2130048, (size_t)4194304, 65536);

    // 9) PAC kernel K1: NS=1, fused exp (single pass over 64 ch)
    pack_d<<<dim3(256, 2), dim3(256), 0, stream>>>(g1, K1, 64, 64, 256, 256, 1, (size_t)0);

    // 10) PacConvT #2: batched MFMA GEMM (N=288, z=2) -> Gin2; batched scatter -> x5
    mg2_k<64, 1, 1><<<dim3(128, 9, 2), dim3(256), 0, stream>>>(
        x3b, wT2b, nullptr, Gin2, 7, 0, 1, 64, 1, (size_t)0,
        (size_t)1048576, (size_t)4718592, 16384);
    pacsc_k<2><<<dim3(64, 16, 2), dim3(256), 0, stream>>>(
        Gin2, K1, b20, x5, 32, 128, 128, (size_t)4718592);

    // 11) double inorm+res on x5 (fp32, feeds final conv)
    istat2_k<<<dim3(64), dim3(256), 0, stream>>>(x5, st5, 65536);
    iapply_k<<<dim3(4096), dim3(256), 0, stream>>>(x5, st5, x5, 65536, 2);

    // 12) final 32->3 @256x256 fp32: NS=4 -> Pf; reduce -> out
    conv3x3_d<3><<<dim3(64, 1, 8), dim3(256), 0, stream>>>(
        x5, W24, nullptr, Pf, 32, 8, 256, 256, 3, 4, (size_t)393216);
    reduce_k<<<dim3(384), dim3(256), 0, stream>>>(Pf, b24, nullptr, out, 65536, 3, 4, 393216);
}